// Round 2
// baseline (1138.453 us; speedup 1.0000x reference)
//
#include <hip/hip_runtime.h>

typedef unsigned short u16;
typedef unsigned int   u32;
typedef short short8 __attribute__((ext_vector_type(8)));
typedef _Float16 half8 __attribute__((ext_vector_type(8)));
typedef float f32x4  __attribute__((ext_vector_type(4)));

#define NN 768
#define N2 (768*768)

__device__ __forceinline__ u16 f2b(float f) {           // fp32 -> bf16 RNE
  u32 u = __float_as_uint(f);
  return (u16)((u + 0x7FFFu + ((u >> 16) & 1u)) >> 16);
}
__device__ __forceinline__ float b2f(u16 h) { return __uint_as_float(((u32)h) << 16); }
__device__ __forceinline__ u16 f2h(float f) {           // fp32 -> fp16 RNE (v_cvt_f16_f32)
  _Float16 h = (_Float16)f;
  return __builtin_bit_cast(u16, h);
}
__device__ __forceinline__ float h2f(u16 h) { return (float)__builtin_bit_cast(_Float16, h); }

// async global->LDS, 16B per lane; LDS dest = wave-uniform base + lane*16
__device__ __forceinline__ void gl_lds16(const void* g, void* lds) {
  __builtin_amdgcn_global_load_lds((__attribute__((address_space(1))) void*)(void*)g,
                                   (__attribute__((address_space(3))) void*)lds, 16, 0, 0);
}

// swizzled frag loads: rows are unpadded 256B / 128B; 16B chunk slot = chunk ^ (row&7)
__device__ __forceinline__ short8 frag256(const u16* base, int row, int k) {
  int c = k >> 3;
  int slot = ((c & 7) ^ (row & 7)) | (c & 8);
  return *(const short8*)(base + row*128 + slot*8);
}
__device__ __forceinline__ short8 frag128(const u16* base, int row, int k) {
  int c = k >> 3;
  int slot = (c ^ row) & 7;
  return *(const short8*)(base + row*64 + slot*8);
}
__device__ __forceinline__ f32x4 mfma_bf(short8 a, short8 b, f32x4 c) {
  return __builtin_amdgcn_mfma_f32_16x16x32_bf16(a, b, c, 0, 0, 0);
}
__device__ __forceinline__ f32x4 mfma_h(short8 a, short8 b, f32x4 c) {
  return __builtin_amdgcn_mfma_f32_16x16x32_f16(
      __builtin_bit_cast(half8, a), __builtin_bit_cast(half8, b), c, 0, 0, 0);
}

// ---------------- k0: weights fp32 -> fp16 ----------------
__global__ void k0_cvt(const float* __restrict__ w0, const float* __restrict__ w1,
                       const float* __restrict__ w2, const float* __restrict__ w3,
                       const float* __restrict__ w4, const float* __restrict__ w5,
                       u16* __restrict__ dst) {
  int idx = blockIdx.x*256 + threadIdx.x;     // 6*16384 total
  int m = idx >> 14, o = idx & 16383;
  const float* s;
  switch (m) { case 0: s=w0; break; case 1: s=w1; break; case 2: s=w2; break;
               case 3: s=w3; break; case 4: s=w4; break; default: s=w5; }
  dst[idx] = f2h(s[o]);
}

// ---------------- k1: LN + 5 projections + transpose ----------------
// wbf order: 0=w_left_gate 1=w_left 2=w_right_gate 3=w_right 4=w_out_gate 5=w_out
__global__ __launch_bounds__(256, 2) void k1_proj(
    const float* __restrict__ x, const float* __restrict__ mask,
    const float* __restrict__ nw, const float* __restrict__ nb,
    const u16* __restrict__ wbf,
    u16* __restrict__ left_t, u16* __restrict__ right_t, u16* __restrict__ gate_ws)
{
  __shared__ __align__(16) u16 As[128*128];   // xn tile (fp16, swizzled)
  __shared__ __align__(16) u16 Bs[128*128];   // weight tile / transpose buffer
  __shared__ float maskL[128];

  const int tid = threadIdx.x, w = tid>>6, l = tid&63;
  const long r0 = (long)blockIdx.x * 128;     // 128 rows (i,k) per block

  if (tid < 128) maskL[tid] = mask[r0 + tid];

  { // LayerNorm: wave w handles rows w*32..w*32+31; lane holds cols 2l,2l+1
    const int c0v = l*2;
    const float nw0 = nw[c0v], nw1 = nw[c0v+1], nb0 = nb[c0v], nb1 = nb[c0v+1];
    for (int m = 0; m < 32; ++m) {
      int row = w*32 + m;
      float2 v = *(const float2*)(x + (r0 + row)*128 + c0v);
      float s = v.x + v.y, s2 = v.x*v.x + v.y*v.y;
      #pragma unroll
      for (int off = 1; off < 64; off <<= 1) {
        s  += __shfl_xor(s,  off, 64);
        s2 += __shfl_xor(s2, off, 64);
      }
      float mu = s * 0.0078125f;
      float rs = rsqrtf(s2 * 0.0078125f - mu*mu + 1e-5f);
      u32 pk = (u32)f2h((v.x - mu)*rs*nw0 + nb0)
             | ((u32)f2h((v.y - mu)*rs*nw1 + nb1) << 16);
      int c = l >> 2, slot = ((c&7)^(row&7)) | (c&8);
      *(u32*)(As + row*128 + slot*8 + (l&3)*2) = pk;
    }
  }
  __syncthreads();

  const int q = l>>4, mm = l&15;

  auto stageB = [&](const u16* wb) {          // 32KB weight tile via global_load_lds
    #pragma unroll
    for (int c2 = 0; c2 < 8; ++c2) {
      int chunk = c2*4 + w;                   // 1KB chunks
      int rowv = chunk*4 + (l>>4);
      int sl = l & 15;
      int g16 = ((sl&7)^(rowv&7)) | (sl&8);
      gl_lds16(wb + rowv*128 + g16*8, Bs + chunk*512);
    }
  };

  f32x4 accA[2][8], accB[2][8];
  auto mfmaInto = [&](f32x4 (&acc)[2][8]) {   // wave: 32 rows x 128 cols
    #pragma unroll
    for (int rt = 0; rt < 2; ++rt)
      #pragma unroll
      for (int ct = 0; ct < 8; ++ct) acc[rt][ct] = (f32x4){0.f,0.f,0.f,0.f};
    #pragma unroll
    for (int ks = 0; ks < 4; ++ks) {
      int k = ks*32 + q*8;
      short8 a0 = frag256(As, w*32 + mm, k);
      short8 a1 = frag256(As, w*32 + 16 + mm, k);
      #pragma unroll
      for (int ct = 0; ct < 8; ++ct) {
        short8 bv = frag256(Bs, ct*16 + mm, k);
        acc[0][ct] = mfma_h(a0, bv, acc[0][ct]);
        acc[1][ct] = mfma_h(a1, bv, acc[1][ct]);
      }
    }
  };

  auto sigmoidAll = [&](f32x4 (&acc)[2][8]) {
    #pragma unroll
    for (int rt = 0; rt < 2; ++rt)
      #pragma unroll
      for (int ct = 0; ct < 8; ++ct)
        #pragma unroll
        for (int r = 0; r < 4; ++r)
          acc[rt][ct][r] = 1.f/(1.f + __expf(-acc[rt][ct][r]));
  };

  auto combineMask = [&](f32x4 (&av)[2][8], f32x4 (&ag)[2][8]) {
    float mk[2][4];
    #pragma unroll
    for (int rt = 0; rt < 2; ++rt)
      #pragma unroll
      for (int r = 0; r < 4; ++r) mk[rt][r] = maskL[w*32 + rt*16 + q*4 + r];
    #pragma unroll
    for (int rt = 0; rt < 2; ++rt)
      #pragma unroll
      for (int ct = 0; ct < 8; ++ct)
        #pragma unroll
        for (int r = 0; r < 4; ++r)
          av[rt][ct][r] *= mk[rt][r] * ag[rt][ct][r];
  };

  auto transposeStore = [&](f32x4 (&av)[2][8], u16* dst) {
    // scatter C (rows=k, cols=d) into Bs as T[d][k] bf16 (256B rows, swizzled)
    #pragma unroll
    for (int rt = 0; rt < 2; ++rt) {
      #pragma unroll
      for (int ct = 0; ct < 8; ++ct) {
        int kl = w*32 + rt*16 + q*4;          // 4 consecutive k = regs
        int d  = ct*16 + mm;
        int c = kl >> 3, slot = ((c&7)^(d&7)) | (c&8);
        u32 p0 = (u32)f2b(av[rt][ct][0]) | ((u32)f2b(av[rt][ct][1])<<16);
        u32 p1 = (u32)f2b(av[rt][ct][2]) | ((u32)f2b(av[rt][ct][3])<<16);
        *(uint2*)(Bs + d*128 + slot*8 + (kl&7)) = make_uint2(p0, p1);
      }
    }
    __syncthreads();
    // cooperative coalesced store: wave w -> d rows w*32..w*32+31, 256B per row
    #pragma unroll
    for (int g = 0; g < 2; ++g) {
      int d = w*32 + g*16 + (l>>2);
      #pragma unroll
      for (int p = 0; p < 4; ++p) {
        int cc = p*4 + (l&3);
        int slot = ((cc&7)^(d&7)) | (cc&8);
        uint4 vv = *(const uint4*)(Bs + d*128 + slot*8);
        *(uint4*)(dst + (long)d*N2 + r0 + cc*8) = vv;
      }
    }
    __syncthreads();
  };

  // ---- left ----
  stageB(wbf + 0*16384); __syncthreads();
  mfmaInto(accA); sigmoidAll(accA);
  __syncthreads();
  stageB(wbf + 1*16384); __syncthreads();
  mfmaInto(accB); combineMask(accB, accA);
  __syncthreads();
  transposeStore(accB, left_t);
  // ---- right ----
  stageB(wbf + 2*16384); __syncthreads();
  mfmaInto(accA); sigmoidAll(accA);
  __syncthreads();
  stageB(wbf + 3*16384); __syncthreads();
  mfmaInto(accB); combineMask(accB, accA);
  __syncthreads();
  transposeStore(accB, right_t);
  // ---- out gate (row-major [r][h] fp16) ----
  stageB(wbf + 4*16384); __syncthreads();
  mfmaInto(accA); sigmoidAll(accA);
  #pragma unroll
  for (int rt = 0; rt < 2; ++rt)
    #pragma unroll
    for (int ct = 0; ct < 8; ++ct)
      #pragma unroll
      for (int r = 0; r < 4; ++r) {
        int row = w*32 + rt*16 + q*4 + r, dd = ct*16 + mm;
        gate_ws[(r0 + row)*128 + dd] = f2h(accA[rt][ct][r]);
      }
}

// ---------------- k2: 128 batched 768^3 NT-GEMMs (bf16, ref semantics) ----------------
__global__ __launch_bounds__(256, 2) void k2_gemm(
    const u16* __restrict__ left_t, const u16* __restrict__ right_t, u16* __restrict__ out_ws)
{
  __shared__ __align__(16) u16 As[128*64];
  __shared__ __align__(16) u16 Bs[128*64];
  const int tid = threadIdx.x, w = tid>>6, l = tid&63;
  int bid = blockIdx.x;
  int d = bid / 36, t36 = bid % 36;
  int it = t36 / 6, jt = t36 % 6;
  const u16* Lb = left_t  + (long)d*N2 + (long)it*128*NN;
  const u16* Rb = right_t + (long)d*N2 + (long)jt*128*NN;
  const int wi = w & 1, wj = w >> 1;
  const int q = l>>4, mm = l&15;
  const int rloc = l>>3, sv = l&7;
  f32x4 acc[4][4];
  #pragma unroll
  for (int a2 = 0; a2 < 4; ++a2)
    #pragma unroll
    for (int b2 = 0; b2 < 4; ++b2) acc[a2][b2] = (f32x4){0.f,0.f,0.f,0.f};

  for (int kt = 0; kt < 12; ++kt) {
    __syncthreads();
    int k0 = kt*64;
    #pragma unroll
    for (int c2 = 0; c2 < 4; ++c2) {
      int chunk = c2*4 + w;
      int row = chunk*8 + rloc;
      int g8 = sv ^ (row & 7);
      gl_lds16(Lb + row*NN + k0 + g8*8, As + chunk*512);
      gl_lds16(Rb + row*NN + k0 + g8*8, Bs + chunk*512);
    }
    __syncthreads();
    #pragma unroll
    for (int kk = 0; kk < 64; kk += 32) {
      int k = kk + q*8;
      short8 af[4], bf[4];
      #pragma unroll
      for (int a2 = 0; a2 < 4; ++a2) af[a2] = frag128(As, wi*64 + a2*16 + mm, k);
      #pragma unroll
      for (int b2 = 0; b2 < 4; ++b2) bf[b2] = frag128(Bs, wj*64 + b2*16 + mm, k);
      #pragma unroll
      for (int a2 = 0; a2 < 4; ++a2)
        #pragma unroll
        for (int b2 = 0; b2 < 4; ++b2)
          acc[a2][b2] = mfma_bf(af[a2], bf[b2], acc[a2][b2]);
    }
  }
  u16* Ob = out_ws + (long)d*N2 + (long)(it*128)*NN + jt*128;
  #pragma unroll
  for (int a2 = 0; a2 < 4; ++a2)
    #pragma unroll
    for (int b2 = 0; b2 < 4; ++b2)
      #pragma unroll
      for (int r = 0; r < 4; ++r)
        Ob[(long)(wi*64 + a2*16 + q*4 + r)*NN + wj*64 + b2*16 + mm] = f2b(acc[a2][b2][r]);
}

// ---------------- k3: out-LN over d + gate + @w_out^T ----------------
__global__ __launch_bounds__(256, 2) void k3_out(
    const u16* __restrict__ out_ws, const u16* __restrict__ gate_ws,
    const float* __restrict__ onw, const float* __restrict__ onb,
    const u16* __restrict__ wbo, float* __restrict__ out)
{
  __shared__ __align__(16) u16 As[64*128];
  __shared__ __align__(16) u16 Bs[128*128];
  __shared__ float P[8][64];
  const int tid = threadIdx.x, w = tid>>6, l = tid&63;
  const int i = blockIdx.y, jt = blockIdx.x;
  const long base = (long)i*NN + jt*64;       // j0 = jt*64; lane owns column j0+l

  float v[32]; float s = 0.f, s2 = 0.f;
  const u16* src = out_ws + base + l;
  #pragma unroll
  for (int dd = 0; dd < 32; ++dd) {           // wave w: channels w*32..+31
    float f = b2f(src[(long)(w*32 + dd)*N2]);
    v[dd] = f; s += f; s2 += f*f;
  }
  P[w][l] = s; P[4+w][l] = s2;
  #pragma unroll
  for (int c2 = 0; c2 < 8; ++c2) {            // stage w_out (async, fp16)
    int chunk = c2*4 + w;
    int rowv = chunk*4 + (l>>4);
    int sl = l&15;
    int g16 = ((sl&7)^(rowv&7)) | (sl&8);
    gl_lds16(wbo + rowv*128 + g16*8, Bs + chunk*512);
  }
  __syncthreads();
  float sum = P[0][l]+P[1][l]+P[2][l]+P[3][l];
  float sq  = P[4][l]+P[5][l]+P[6][l]+P[7][l];
  float mu = sum * 0.0078125f;
  float rs = rsqrtf(sq * 0.0078125f - mu*mu + 1e-5f);

  const u16* gp = gate_ws + (base + l)*128 + w*32;
  #pragma unroll
  for (int hh = 0; hh < 32; hh += 2) {
    int h = w*32 + hh;
    u32 gpr = *(const u32*)(gp + hh);
    float g0 = h2f((u16)gpr), g1 = h2f((u16)(gpr>>16));
    float a0 = ((v[hh]   - mu)*rs*onw[h]   + onb[h])   * g0;
    float a1 = ((v[hh+1] - mu)*rs*onw[h+1] + onb[h+1]) * g1;
    u32 pk = (u32)f2h(a0) | ((u32)f2h(a1)<<16);
    int c = h >> 3, slot = ((c&7)^(l&7)) | (c&8);
    *(u32*)(As + l*128 + slot*8 + (h&7)) = pk;
  }
  __syncthreads();

  const int q = l>>4, mm = l&15;
  f32x4 acc[8];
  #pragma unroll
  for (int b2 = 0; b2 < 8; ++b2) acc[b2] = (f32x4){0.f,0.f,0.f,0.f};
  #pragma unroll
  for (int ks = 0; ks < 4; ++ks) {
    int k = ks*32 + q*8;
    short8 af = frag256(As, w*16 + mm, k);
    #pragma unroll
    for (int b2 = 0; b2 < 8; ++b2)
      acc[b2] = mfma_h(af, frag256(Bs, b2*16 + mm, k), acc[b2]);
  }
  float* ob = out + (base + w*16)*128;
  #pragma unroll
  for (int b2 = 0; b2 < 8; ++b2)
    #pragma unroll
    for (int r = 0; r < 4; ++r)
      ob[(long)(q*4 + r)*128 + b2*16 + mm] = acc[b2][r];
}

extern "C" void kernel_launch(void* const* d_in, const int* in_sizes, int n_in,
                              void* d_out, int out_size, void* d_ws, size_t ws_size,
                              hipStream_t stream) {
  const float* x    = (const float*)d_in[0];
  const float* mask = (const float*)d_in[1];
  const float* nw   = (const float*)d_in[2];
  const float* nb   = (const float*)d_in[3];
  const float* wl   = (const float*)d_in[4];
  const float* wr   = (const float*)d_in[5];
  const float* wlg  = (const float*)d_in[6];
  const float* wrg  = (const float*)d_in[7];
  const float* wog  = (const float*)d_in[8];
  const float* onw  = (const float*)d_in[9];
  const float* onb  = (const float*)d_in[10];
  const float* wo   = (const float*)d_in[11];

  // ws layout: left_t[128][768][768] bf16, right_t bf16, gate[r][128] fp16,
  //            out_ws[128][768][768] bf16, wbf[6][128][128] fp16
  if (ws_size < (size_t)4*N2*128*2 + 6*16384*2) return;
  u16* left_t  = (u16*)d_ws;
  u16* right_t = left_t  + (size_t)N2*128;
  u16* gate_ws = right_t + (size_t)N2*128;
  u16* out_ws  = gate_ws + (size_t)N2*128;
  u16* wbf     = out_ws  + (size_t)N2*128;

  k0_cvt<<<384, 256, 0, stream>>>(wlg, wl, wrg, wr, wog, wo, wbf);
  k1_proj<<<4608, 256, 0, stream>>>(x, mask, nw, nb, wbf, left_t, right_t, gate_ws);
  k2_gemm<<<4608, 256, 0, stream>>>(left_t, right_t, out_ws);
  k3_out<<<dim3(12, 768), 256, 0, stream>>>(out_ws, gate_ws, onw, onb, wbf + 5*16384, (float*)d_out);
}